// Round 1
// baseline (2259.365 us; speedup 1.0000x reference)
//
#include <hip/hip_runtime.h>
#include <math.h>

#define CIN   32
#define COUT  64
#define DD    20
#define NSP   8000      // 20*20*20
#define BB    2
#define EPSN  1e-5f
#define SLOPE 0.01f

#define SPLITS 8
#define KPS    (NSP / SPLITS)   // 1000
#define QBLK   256
#define NQB    32               // ceil(8000/256)
#define KTILE  8                // divides KPS

// ---------------- Conv3d k=3 s=1 SAME + bias ----------------
__global__ void conv3d_k(const float* __restrict__ x, const float* __restrict__ w,
                         const float* __restrict__ bias, float* __restrict__ y) {
    int idx = blockIdx.x * blockDim.x + threadIdx.x;
    if (idx >= BB * COUT * NSP) return;
    int w_ = idx % DD;
    int h_ = (idx / DD) % DD;
    int d_ = (idx / (DD * DD)) % DD;
    int co = (idx / NSP) % COUT;
    int b  = idx / (NSP * COUT);

    float s = bias[co];
    const float* wb = w + co * (CIN * 27);
    const float* xb = x + b * (CIN * NSP);
    for (int kd = 0; kd < 3; ++kd) {
        int zd = d_ + kd - 1;
        if (zd < 0 || zd >= DD) continue;
        for (int kh = 0; kh < 3; ++kh) {
            int zh = h_ + kh - 1;
            if (zh < 0 || zh >= DD) continue;
            for (int kw = 0; kw < 3; ++kw) {
                int zw = w_ + kw - 1;
                if (zw < 0 || zw >= DD) continue;
                int xoff = (zd * DD + zh) * DD + zw;
                int woff = (kd * 3 + kh) * 3 + kw;
                #pragma unroll
                for (int ci = 0; ci < CIN; ++ci)
                    s += xb[ci * NSP + xoff] * wb[ci * 27 + woff];
            }
        }
    }
    y[idx] = s;
}

// ---------------- InstanceNorm stats: one block per (b,c) ----------------
__global__ void instnorm_stats_k(const float* __restrict__ y, float* __restrict__ stats) {
    int bc = blockIdx.x;                 // 0..127
    const float* yb = y + (size_t)bc * NSP;
    float s = 0.f, ss = 0.f;
    for (int i = threadIdx.x; i < NSP; i += blockDim.x) {
        float v = yb[i];
        s += v; ss += v * v;
    }
    __shared__ float rs[256], rss[256];
    rs[threadIdx.x] = s; rss[threadIdx.x] = ss;
    __syncthreads();
    for (int off = 128; off > 0; off >>= 1) {
        if (threadIdx.x < off) {
            rs[threadIdx.x]  += rs[threadIdx.x + off];
            rss[threadIdx.x] += rss[threadIdx.x + off];
        }
        __syncthreads();
    }
    if (threadIdx.x == 0) {
        float mean = rs[0] / (float)NSP;
        float var  = rss[0] / (float)NSP - mean * mean;
        stats[bc * 2 + 0] = mean;
        stats[bc * 2 + 1] = rsqrtf(var + EPSN);
    }
}

// ---------------- normalize + affine + LeakyReLU (in place) ----------------
__global__ void norm_lrelu_k(float* __restrict__ y, const float* __restrict__ stats,
                             const float* __restrict__ gamma, const float* __restrict__ beta) {
    int idx = blockIdx.x * blockDim.x + threadIdx.x;
    if (idx >= BB * COUT * NSP) return;
    int bc = idx / NSP;
    int c  = bc % COUT;
    float mean = stats[bc * 2 + 0];
    float rstd = stats[bc * 2 + 1];
    float v = (y[idx] - mean) * rstd * gamma[c] + beta[c];
    y[idx] = v >= 0.f ? v : SLOPE * v;
}

// ---------------- QKV projections ----------------
__global__ void qkv_k(const float* __restrict__ f,
                      const float* __restrict__ wq, const float* __restrict__ bq,
                      const float* __restrict__ wk, const float* __restrict__ bk,
                      const float* __restrict__ wv, const float* __restrict__ bv,
                      float* __restrict__ q, float* __restrict__ k, float* __restrict__ v) {
    int idx = blockIdx.x * blockDim.x + threadIdx.x;   // over B*COUT*NSP
    if (idx >= BB * COUT * NSP) return;
    int n = idx % NSP;
    int o = (idx / NSP) % COUT;
    int b = idx / (NSP * COUT);
    const float* fb = f + (size_t)b * COUT * NSP + n;
    float aq = bq[o], ak = bk[o], av = bv[o];
    #pragma unroll 16
    for (int c = 0; c < COUT; ++c) {
        float fc = fb[c * NSP];
        aq += wq[o * COUT + c] * fc;
        ak += wk[o * COUT + c] * fc;
        av += wv[o * COUT + c] * fc;
    }
    q[idx] = aq; k[idx] = ak; v[idx] = av;
}

// ---------------- flash attention pass 1 (split-K, online softmax) ----------------
__global__ void __launch_bounds__(QBLK) attn_pass1_k(
        const float* __restrict__ Q, const float* __restrict__ K, const float* __restrict__ V,
        float* __restrict__ pm, float* __restrict__ pl, float* __restrict__ pacc) {
    int bid   = blockIdx.x;             // B * NQB * SPLITS
    int split = bid % SPLITS;
    int qb    = (bid / SPLITS) % NQB;
    int b     = bid / (SPLITS * NQB);
    int qi    = qb * QBLK + threadIdx.x;
    bool valid = qi < NSP;
    int qc = valid ? qi : 0;

    const float* Qb = Q + (size_t)b * COUT * NSP;
    const float* Kb = K + (size_t)b * COUT * NSP;
    const float* Vb = V + (size_t)b * COUT * NSP;

    float qreg[COUT];
    #pragma unroll
    for (int c = 0; c < COUT; ++c) qreg[c] = Qb[c * NSP + qc];

    float m = -1e30f, l = 0.f;
    float acc[COUT];
    #pragma unroll
    for (int c = 0; c < COUT; ++c) acc[c] = 0.f;

    int k0 = split * KPS;
    for (int kt = 0; kt < KPS; kt += KTILE) {
        // logits for KTILE keys (K reads are wave-uniform -> scalar loads)
        float s[KTILE];
        #pragma unroll
        for (int j = 0; j < KTILE; ++j) s[j] = 0.f;
        #pragma unroll
        for (int c = 0; c < COUT; ++c) {
            float qv = qreg[c];
            const float* krow = Kb + c * NSP + k0 + kt;
            #pragma unroll
            for (int j = 0; j < KTILE; ++j) s[j] += qv * krow[j];
        }
        // online softmax update
        float tmax = s[0];
        #pragma unroll
        for (int j = 1; j < KTILE; ++j) tmax = fmaxf(tmax, s[j]);
        float newm  = fmaxf(m, tmax);
        float scale = __expf(m - newm);
        l *= scale;
        #pragma unroll
        for (int c = 0; c < COUT; ++c) acc[c] *= scale;
        float p[KTILE];
        #pragma unroll
        for (int j = 0; j < KTILE; ++j) { p[j] = __expf(s[j] - newm); l += p[j]; }
        m = newm;
        // PV accumulate (V reads wave-uniform -> scalar loads)
        #pragma unroll
        for (int c = 0; c < COUT; ++c) {
            const float* vrow = Vb + c * NSP + k0 + kt;
            float a = acc[c];
            #pragma unroll
            for (int j = 0; j < KTILE; ++j) a += p[j] * vrow[j];
            acc[c] = a;
        }
    }

    if (valid) {
        size_t base = (size_t)b * SPLITS + split;
        pm[base * NSP + qi] = m;
        pl[base * NSP + qi] = l;
        float* pa = pacc + base * COUT * NSP + qi;
        #pragma unroll
        for (int c = 0; c < COUT; ++c) pa[(size_t)c * NSP] = acc[c];
    }
}

// ---------------- combine split-K partials ----------------
__global__ void attn_combine_k(const float* __restrict__ pm, const float* __restrict__ pl,
                               const float* __restrict__ pacc, float* __restrict__ out) {
    int idx = blockIdx.x * blockDim.x + threadIdx.x;   // over B*COUT*NSP
    if (idx >= BB * COUT * NSP) return;
    int n = idx % NSP;
    int c = (idx / NSP) % COUT;
    int b = idx / (NSP * COUT);
    float M = -1e30f;
    #pragma unroll
    for (int j = 0; j < SPLITS; ++j)
        M = fmaxf(M, pm[((size_t)b * SPLITS + j) * NSP + n]);
    float L = 0.f, O = 0.f;
    #pragma unroll
    for (int j = 0; j < SPLITS; ++j) {
        size_t base = (size_t)b * SPLITS + j;
        float wgt = __expf(pm[base * NSP + n] - M);
        L += pl[base * NSP + n] * wgt;
        O += pacc[(base * COUT + c) * NSP + n] * wgt;
    }
    out[idx] = O / L;
}

// ---------------- launch ----------------
extern "C" void kernel_launch(void* const* d_in, const int* in_sizes, int n_in,
                              void* d_out, int out_size, void* d_ws, size_t ws_size,
                              hipStream_t stream) {
    const float* x      = (const float*)d_in[0];
    const float* conv_w = (const float*)d_in[1];
    const float* conv_b = (const float*)d_in[2];
    const float* gamma  = (const float*)d_in[3];
    const float* beta   = (const float*)d_in[4];
    const float* wq     = (const float*)d_in[5];
    const float* bq     = (const float*)d_in[6];
    const float* wk     = (const float*)d_in[7];
    const float* bk     = (const float*)d_in[8];
    const float* wv     = (const float*)d_in[9];
    const float* bv     = (const float*)d_in[10];
    float* out = (float*)d_out;

    const int ELEMS = BB * COUT * NSP;      // 1,024,000
    float* ws    = (float*)d_ws;
    float* y     = ws;                      // ELEMS
    float* q     = y + ELEMS;
    float* k     = q + ELEMS;
    float* v     = k + ELEMS;
    float* stats = v + ELEMS;               // 256
    float* pm    = stats + 256;             // B*SPLITS*NSP = 128,000
    float* pl    = pm + BB * SPLITS * NSP;
    float* pacc  = pl + BB * SPLITS * NSP;  // B*SPLITS*COUT*NSP = 8,192,000

    int blocks = (ELEMS + 255) / 256;       // 4000

    conv3d_k<<<blocks, 256, 0, stream>>>(x, conv_w, conv_b, y);
    instnorm_stats_k<<<BB * COUT, 256, 0, stream>>>(y, stats);
    norm_lrelu_k<<<blocks, 256, 0, stream>>>(y, stats, gamma, beta);
    qkv_k<<<blocks, 256, 0, stream>>>(y, wq, bq, wk, bk, wv, bv, q, k, v);
    attn_pass1_k<<<BB * NQB * SPLITS, QBLK, 0, stream>>>(q, k, v, pm, pl, pacc);
    attn_combine_k<<<blocks, 256, 0, stream>>>(pm, pl, pacc, out);
}

// Round 2
// 475.345 us; speedup vs baseline: 4.7531x; 4.7531x over previous
//
#include <hip/hip_runtime.h>
#include <math.h>

#define CIN   32
#define COUT  64
#define DD    20
#define NSP   8000      // 20*20*20
#define BB    2
#define EPSN  1e-5f
#define SLOPE 0.01f

#define SPLITS 5
#define KPS    (NSP / SPLITS)   // 1600
#define NKT    (KPS / 32)       // 50 k-tiles of 32
#define QPB    125              // q-tile pairs per batch (2 waves/block, 32 q-rows each)

typedef float  f32x16 __attribute__((ext_vector_type(16)));
typedef short  short8 __attribute__((ext_vector_type(8)));

__device__ __forceinline__ unsigned short f2bf_rne(float x) {
    unsigned u = __float_as_uint(x);
    unsigned r = (u + 0x7FFFu + ((u >> 16) & 1u)) >> 16;
    return (unsigned short)r;
}
__device__ __forceinline__ float bf2f(unsigned short h) {
    return __uint_as_float(((unsigned)h) << 16);
}
__device__ __forceinline__ short8 ld_frag(const unsigned short* p) {
    uint4 t = *reinterpret_cast<const uint4*>(p);
    return __builtin_bit_cast(short8, t);
}

// ---------------- Conv3d k=3 s=1 SAME + bias ----------------
__global__ void conv3d_k(const float* __restrict__ x, const float* __restrict__ w,
                         const float* __restrict__ bias, float* __restrict__ y) {
    int idx = blockIdx.x * blockDim.x + threadIdx.x;
    if (idx >= BB * COUT * NSP) return;
    int w_ = idx % DD;
    int h_ = (idx / DD) % DD;
    int d_ = (idx / (DD * DD)) % DD;
    int co = (idx / NSP) % COUT;
    int b  = idx / (NSP * COUT);

    float s = bias[co];
    const float* wb = w + co * (CIN * 27);
    const float* xb = x + b * (CIN * NSP);
    for (int kd = 0; kd < 3; ++kd) {
        int zd = d_ + kd - 1;
        if (zd < 0 || zd >= DD) continue;
        for (int kh = 0; kh < 3; ++kh) {
            int zh = h_ + kh - 1;
            if (zh < 0 || zh >= DD) continue;
            for (int kw = 0; kw < 3; ++kw) {
                int zw = w_ + kw - 1;
                if (zw < 0 || zw >= DD) continue;
                int xoff = (zd * DD + zh) * DD + zw;
                int woff = (kd * 3 + kh) * 3 + kw;
                #pragma unroll
                for (int ci = 0; ci < CIN; ++ci)
                    s += xb[ci * NSP + xoff] * wb[ci * 27 + woff];
            }
        }
    }
    y[idx] = s;
}

// ---------------- InstanceNorm stats: one block per (b,c) ----------------
__global__ void instnorm_stats_k(const float* __restrict__ y, float* __restrict__ stats) {
    int bc = blockIdx.x;                 // 0..127
    const float* yb = y + (size_t)bc * NSP;
    float s = 0.f, ss = 0.f;
    for (int i = threadIdx.x; i < NSP; i += blockDim.x) {
        float v = yb[i];
        s += v; ss += v * v;
    }
    __shared__ float rs[256], rss[256];
    rs[threadIdx.x] = s; rss[threadIdx.x] = ss;
    __syncthreads();
    for (int off = 128; off > 0; off >>= 1) {
        if (threadIdx.x < off) {
            rs[threadIdx.x]  += rs[threadIdx.x + off];
            rss[threadIdx.x] += rss[threadIdx.x + off];
        }
        __syncthreads();
    }
    if (threadIdx.x == 0) {
        float mean = rs[0] / (float)NSP;
        float var  = rss[0] / (float)NSP - mean * mean;
        stats[bc * 2 + 0] = mean;
        stats[bc * 2 + 1] = rsqrtf(var + EPSN);
    }
}

// ---------------- normalize + affine + LeakyReLU (in place) ----------------
__global__ void norm_lrelu_k(float* __restrict__ y, const float* __restrict__ stats,
                             const float* __restrict__ gamma, const float* __restrict__ beta) {
    int idx = blockIdx.x * blockDim.x + threadIdx.x;
    if (idx >= BB * COUT * NSP) return;
    int bc = idx / NSP;
    int c  = bc % COUT;
    float mean = stats[bc * 2 + 0];
    float rstd = stats[bc * 2 + 1];
    float v = (y[idx] - mean) * rstd * gamma[c] + beta[c];
    y[idx] = v >= 0.f ? v : SLOPE * v;
}

// ---------------- QKV projections -> bf16 hi/lo operand layouts ----------------
// Qhi/Qlo/Khi/Klo: [B][N][C] bf16 (row-per-token, 16B fragment loads)
// Vb:              [B][C][N] bf16 (row-per-channel, 16B fragment loads)
__global__ void qkv_k(const float* __restrict__ f,
                      const float* __restrict__ wq, const float* __restrict__ bq,
                      const float* __restrict__ wk, const float* __restrict__ bk,
                      const float* __restrict__ wv, const float* __restrict__ bv,
                      unsigned short* __restrict__ Qhi, unsigned short* __restrict__ Qlo,
                      unsigned short* __restrict__ Khi, unsigned short* __restrict__ Klo,
                      unsigned short* __restrict__ Vb) {
    int idx = blockIdx.x * blockDim.x + threadIdx.x;   // over B*COUT*NSP, n fastest
    if (idx >= BB * COUT * NSP) return;
    int n = idx % NSP;
    int o = (idx / NSP) % COUT;
    int b = idx / (NSP * COUT);
    const float* fb = f + (size_t)b * COUT * NSP + n;
    float aq = bq[o], ak = bk[o], av = bv[o];
    #pragma unroll 16
    for (int c = 0; c < COUT; ++c) {
        float fc = fb[c * NSP];
        aq += wq[o * COUT + c] * fc;
        ak += wk[o * COUT + c] * fc;
        av += wv[o * COUT + c] * fc;
    }
    size_t tq = ((size_t)(b * NSP + n)) * COUT + o;
    unsigned short qh = f2bf_rne(aq);
    Qhi[tq] = qh;
    Qlo[tq] = f2bf_rne(aq - bf2f(qh));
    unsigned short kh = f2bf_rne(ak);
    Khi[tq] = kh;
    Klo[tq] = f2bf_rne(ak - bf2f(kh));
    Vb[(size_t)(b * COUT + o) * NSP + n] = f2bf_rne(av);
}

// ---------------- flash attention pass 1: MFMA, split-K, online softmax ----------------
// Per wave: 32 q-rows. S^T = K.Q^T (q = lane&31 col), O^T = V^T.P^T (q = lane&31 col).
__global__ __launch_bounds__(128) void attn_pass1_mfma(
        const unsigned short* __restrict__ Qhi, const unsigned short* __restrict__ Qlo,
        const unsigned short* __restrict__ Khi, const unsigned short* __restrict__ Klo,
        const unsigned short* __restrict__ Vb,
        float* __restrict__ pm, float* __restrict__ pl, float* __restrict__ pacc) {
    int bid   = blockIdx.x;
    int split = bid % SPLITS;
    int qpair = (bid / SPLITS) % QPB;
    int b     = bid / (SPLITS * QPB);
    int wave  = threadIdx.x >> 6;
    int lane  = threadIdx.x & 63;
    int col   = lane & 31;          // q index within tile (and c-row for O^T A-operand)
    int half  = lane >> 5;
    int q0    = (qpair * 2 + wave) * 32;
    int n0base = split * KPS;

    // Q fragments (B-operand): col=lane&31 -> q ; elems = dim chunk c*16 + half*8 + 0..7
    short8 qfh[4], qfl[4];
    {
        const unsigned short* qp  = Qhi + ((size_t)(b * NSP + q0 + col)) * COUT + half * 8;
        const unsigned short* qp2 = Qlo + ((size_t)(b * NSP + q0 + col)) * COUT + half * 8;
        #pragma unroll
        for (int c = 0; c < 4; ++c) {
            qfh[c] = ld_frag(qp  + c * 16);
            qfl[c] = ld_frag(qp2 + c * 16);
        }
    }

    f32x16 oacc0 = {};     // O^T rows c=0..31
    f32x16 oacc1 = {};     // O^T rows c=32..63
    float m = -3e38f, lsum = 0.f;

    for (int t = 0; t < NKT; ++t) {
        int n0 = n0base + t * 32;
        const unsigned short* kp  = Khi + ((size_t)(b * NSP + n0 + col)) * COUT + half * 8;
        const unsigned short* kp2 = Klo + ((size_t)(b * NSP + n0 + col)) * COUT + half * 8;
        f32x16 s = {};
        #pragma unroll
        for (int c = 0; c < 4; ++c) {
            short8 kfh = ld_frag(kp  + c * 16);
            short8 kfl = ld_frag(kp2 + c * 16);
            s = __builtin_amdgcn_mfma_f32_32x32x16_bf16(kfh, qfh[c], s, 0, 0, 0);
            s = __builtin_amdgcn_mfma_f32_32x32x16_bf16(kfh, qfl[c], s, 0, 0, 0);
            s = __builtin_amdgcn_mfma_f32_32x32x16_bf16(kfl, qfh[c], s, 0, 0, 0);
        }
        // online softmax (per-lane q-column; k rows split with lane^32)
        float tmax = s[0];
        #pragma unroll
        for (int r = 1; r < 16; ++r) tmax = fmaxf(tmax, s[r]);
        tmax = fmaxf(tmax, __shfl_xor(tmax, 32, 64));
        if (__any(tmax > m)) {
            float newm  = fmaxf(m, tmax);
            float scale = __expf(m - newm);
            lsum *= scale;
            #pragma unroll
            for (int r = 0; r < 16; ++r) { oacc0[r] *= scale; oacc1[r] *= scale; }
            m = newm;
        }
        float p[16]; float ls = 0.f;
        #pragma unroll
        for (int r = 0; r < 16; ++r) { p[r] = __expf(s[r] - m); ls += p[r]; }
        lsum += ls;
        // P^T B-fragment build: cvt_pk pairs + exchange halves (lane^32)
        unsigned W[8], X[8];
        #pragma unroll
        for (int j = 0; j < 8; ++j)
            asm("v_cvt_pk_bf16_f32 %0, %1, %2" : "=v"(W[j]) : "v"(p[2 * j]), "v"(p[2 * j + 1]));
        #pragma unroll
        for (int j = 0; j < 8; ++j) X[j] = (unsigned)__shfl_xor((int)W[j], 32, 64);
        uint4 u0, u1;
        if (half == 0) { u0 = make_uint4(W[0], W[1], X[0], X[1]); u1 = make_uint4(W[4], W[5], X[4], X[5]); }
        else           { u0 = make_uint4(X[2], X[3], W[2], W[3]); u1 = make_uint4(X[6], X[7], W[6], W[7]); }
        short8 pf0 = __builtin_bit_cast(short8, u0);   // k = n0 + 0..15
        short8 pf1 = __builtin_bit_cast(short8, u1);   // k = n0 + 16..31
        // V^T A-fragments: row c = lane&31 (+32 for oacc1), k elems consecutive
        const unsigned short* vp = Vb + ((size_t)(b * COUT + col)) * NSP + n0 + half * 8;
        short8 v00 = ld_frag(vp);
        short8 v01 = ld_frag(vp + 16);
        short8 v10 = ld_frag(vp + (size_t)32 * NSP);
        short8 v11 = ld_frag(vp + (size_t)32 * NSP + 16);
        oacc0 = __builtin_amdgcn_mfma_f32_32x32x16_bf16(v00, pf0, oacc0, 0, 0, 0);
        oacc0 = __builtin_amdgcn_mfma_f32_32x32x16_bf16(v01, pf1, oacc0, 0, 0, 0);
        oacc1 = __builtin_amdgcn_mfma_f32_32x32x16_bf16(v10, pf0, oacc1, 0, 0, 0);
        oacc1 = __builtin_amdgcn_mfma_f32_32x32x16_bf16(v11, pf1, oacc1, 0, 0, 0);
    }

    float lfull = lsum + __shfl_xor(lsum, 32, 64);
    size_t base = (size_t)b * SPLITS + split;
    if (lane < 32) {
        pm[base * NSP + q0 + col] = m;
        pl[base * NSP + q0 + col] = lfull;
    }
    float* pa = pacc + base * (size_t)(COUT * NSP) + q0 + col;
    #pragma unroll
    for (int r = 0; r < 16; ++r) {
        int crow = (r & 3) + 8 * (r >> 2) + 4 * half;
        pa[(size_t)crow * NSP]        = oacc0[r];
        pa[(size_t)(crow + 32) * NSP] = oacc1[r];
    }
}

// ---------------- combine split-K partials ----------------
__global__ void attn_combine_k(const float* __restrict__ pm, const float* __restrict__ pl,
                               const float* __restrict__ pacc, float* __restrict__ out) {
    int idx = blockIdx.x * blockDim.x + threadIdx.x;   // over B*COUT*NSP
    if (idx >= BB * COUT * NSP) return;
    int n = idx % NSP;
    int c = (idx / NSP) % COUT;
    int b = idx / (NSP * COUT);
    float M = -1e30f;
    #pragma unroll
    for (int j = 0; j < SPLITS; ++j)
        M = fmaxf(M, pm[((size_t)b * SPLITS + j) * NSP + n]);
    float L = 0.f, O = 0.f;
    #pragma unroll
    for (int j = 0; j < SPLITS; ++j) {
        size_t base = (size_t)b * SPLITS + j;
        float wgt = __expf(pm[base * NSP + n] - M);
        L += pl[base * NSP + n] * wgt;
        O += pacc[(base * COUT + c) * NSP + n] * wgt;
    }
    out[idx] = O / L;
}

// ---------------- launch ----------------
extern "C" void kernel_launch(void* const* d_in, const int* in_sizes, int n_in,
                              void* d_out, int out_size, void* d_ws, size_t ws_size,
                              hipStream_t stream) {
    const float* x      = (const float*)d_in[0];
    const float* conv_w = (const float*)d_in[1];
    const float* conv_b = (const float*)d_in[2];
    const float* gamma  = (const float*)d_in[3];
    const float* beta   = (const float*)d_in[4];
    const float* wq     = (const float*)d_in[5];
    const float* bq     = (const float*)d_in[6];
    const float* wk     = (const float*)d_in[7];
    const float* bk     = (const float*)d_in[8];
    const float* wv     = (const float*)d_in[9];
    const float* bv     = (const float*)d_in[10];
    float* out = (float*)d_out;

    const int ELEMS = BB * COUT * NSP;      // 1,024,000
    char* w8 = (char*)d_ws;
    float* y     = (float*)w8;                          // 4,096,000 B
    float* stats = (float*)(w8 + 4096000);              // 1,024 B
    unsigned short* Qhi = (unsigned short*)(w8 + 4097024);
    unsigned short* Qlo = Qhi + (size_t)ELEMS;          // each 2,048,000 B
    unsigned short* Khi = Qlo + (size_t)ELEMS;
    unsigned short* Klo = Khi + (size_t)ELEMS;
    unsigned short* Vb  = Klo + (size_t)ELEMS;
    float* pm   = (float*)(Vb + (size_t)ELEMS);
    float* pl   = pm + (size_t)BB * SPLITS * NSP;       // 80,000 each
    float* pacc = pl + (size_t)BB * SPLITS * NSP;       // 20,480,000 B

    int blocks = (ELEMS + 255) / 256;       // 4000

    conv3d_k<<<blocks, 256, 0, stream>>>(x, conv_w, conv_b, y);
    instnorm_stats_k<<<BB * COUT, 256, 0, stream>>>(y, stats);
    norm_lrelu_k<<<blocks, 256, 0, stream>>>(y, stats, gamma, beta);
    qkv_k<<<blocks, 256, 0, stream>>>(y, wq, bq, wk, bk, wv, bv,
                                      Qhi, Qlo, Khi, Klo, Vb);
    attn_pass1_mfma<<<BB * QPB * SPLITS, 128, 0, stream>>>(Qhi, Qlo, Khi, Klo, Vb,
                                                           pm, pl, pacc);
    attn_combine_k<<<blocks, 256, 0, stream>>>(pm, pl, pacc, out);
}

// Round 3
// 286.884 us; speedup vs baseline: 7.8755x; 1.6569x over previous
//
#include <hip/hip_runtime.h>
#include <math.h>

#define CIN   32
#define COUT  64
#define DD    20
#define PD    22        // padded dim
#define PSP   (PD*PD*PD)   // 10648
#define NSP   8000      // 20*20*20
#define BB    2
#define EPSN  1e-5f
#define SLOPE 0.01f

#define SPLITS 5
#define KPS    (NSP / SPLITS)   // 1600
#define NKT    (KPS / 32)       // 50 k-tiles of 32
#define QPB    125              // q-tile pairs per batch (2 waves/block, 32 q-rows each)

#define COG 8                   // conv: output channels per thread
#define OG  8                   // qkv: output channels per thread

typedef float  f32x16 __attribute__((ext_vector_type(16)));
typedef short  short8 __attribute__((ext_vector_type(8)));

__device__ __forceinline__ unsigned short f2bf_rne(float x) {
    unsigned u = __float_as_uint(x);
    unsigned r = (u + 0x7FFFu + ((u >> 16) & 1u)) >> 16;
    return (unsigned short)r;
}
__device__ __forceinline__ float bf2f(unsigned short h) {
    return __uint_as_float(((unsigned)h) << 16);
}
__device__ __forceinline__ short8 ld_frag(const unsigned short* p) {
    uint4 t = *reinterpret_cast<const uint4*>(p);
    return __builtin_bit_cast(short8, t);
}

// ---------------- zero-pad x into [B][CIN][22][22][22] ----------------
__global__ void pad_k(const float* __restrict__ x, float* __restrict__ xp) {
    int idx = blockIdx.x * blockDim.x + threadIdx.x;
    if (idx >= BB * CIN * PSP) return;
    int pw = idx % PD;
    int ph = (idx / PD) % PD;
    int pd = (idx / (PD * PD)) % PD;
    int bc = idx / PSP;
    float v = 0.f;
    if (pw >= 1 && pw <= DD && ph >= 1 && ph <= DD && pd >= 1 && pd <= DD)
        v = x[(size_t)bc * NSP + ((size_t)(pd - 1) * DD + (ph - 1)) * DD + (pw - 1)];
    xp[idx] = v;
}

// ---------------- Conv3d k=3 s=1 SAME + bias (padded input, reg-blocked) ----------------
// grid: b * 8 co-groups * 32 voxel-blocks ; thread = 1 voxel, COG output channels
__global__ __launch_bounds__(256) void conv3d_k(const float* __restrict__ xp,
                                                const float* __restrict__ w,
                                                const float* __restrict__ bias,
                                                float* __restrict__ y) {
    int blk = blockIdx.x;
    int vb  = blk & 31;
    int cg  = (blk >> 5) & 7;       // uniform co-group
    int b   = blk >> 8;
    int vox = vb * 256 + threadIdx.x;
    bool valid = vox < NSP;
    int v  = valid ? vox : 0;
    int w_ = v % DD;
    int h_ = (v / DD) % DD;
    int d_ = v / (DD * DD);
    int pvox = ((d_ + 1) * PD + (h_ + 1)) * PD + (w_ + 1);
    const float* xb = xp + (size_t)b * CIN * PSP + pvox;

    float acc[COG];
    #pragma unroll
    for (int j = 0; j < COG; ++j) acc[j] = 0.f;

    for (int ci = 0; ci < CIN; ++ci) {
        const float* xc = xb + (size_t)ci * PSP;
        float xv[27];
        #pragma unroll
        for (int kd = 0; kd < 3; ++kd)
            #pragma unroll
            for (int kh = 0; kh < 3; ++kh)
                #pragma unroll
                for (int kw = 0; kw < 3; ++kw)
                    xv[(kd * 3 + kh) * 3 + kw] =
                        xc[(kd - 1) * (PD * PD) + (kh - 1) * PD + (kw - 1)];
        #pragma unroll
        for (int j = 0; j < COG; ++j) {
            int co = cg * COG + j;                       // uniform
            const float* wr = w + ((size_t)co * CIN + ci) * 27;
            float a = acc[j];
            #pragma unroll
            for (int t = 0; t < 27; ++t) a += xv[t] * wr[t];
            acc[j] = a;
        }
    }
    if (valid) {
        #pragma unroll
        for (int j = 0; j < COG; ++j) {
            int co = cg * COG + j;
            y[((size_t)b * COUT + co) * NSP + vox] = acc[j] + bias[co];
        }
    }
}

// ---------------- InstanceNorm stats: one block per (b,c) ----------------
__global__ void instnorm_stats_k(const float* __restrict__ y, float* __restrict__ stats) {
    int bc = blockIdx.x;                 // 0..127
    const float* yb = y + (size_t)bc * NSP;
    float s = 0.f, ss = 0.f;
    for (int i = threadIdx.x; i < NSP; i += blockDim.x) {
        float v = yb[i];
        s += v; ss += v * v;
    }
    __shared__ float rs[256], rss[256];
    rs[threadIdx.x] = s; rss[threadIdx.x] = ss;
    __syncthreads();
    for (int off = 128; off > 0; off >>= 1) {
        if (threadIdx.x < off) {
            rs[threadIdx.x]  += rs[threadIdx.x + off];
            rss[threadIdx.x] += rss[threadIdx.x + off];
        }
        __syncthreads();
    }
    if (threadIdx.x == 0) {
        float mean = rs[0] / (float)NSP;
        float var  = rss[0] / (float)NSP - mean * mean;
        stats[bc * 2 + 0] = mean;
        stats[bc * 2 + 1] = rsqrtf(var + EPSN);
    }
}

// ---------------- normalize + affine + LeakyReLU (in place) ----------------
__global__ void norm_lrelu_k(float* __restrict__ y, const float* __restrict__ stats,
                             const float* __restrict__ gamma, const float* __restrict__ beta) {
    int idx = blockIdx.x * blockDim.x + threadIdx.x;
    if (idx >= BB * COUT * NSP) return;
    int bc = idx / NSP;
    int c  = bc % COUT;
    float mean = stats[bc * 2 + 0];
    float rstd = stats[bc * 2 + 1];
    float v = (y[idx] - mean) * rstd * gamma[c] + beta[c];
    y[idx] = v >= 0.f ? v : SLOPE * v;
}

// ---------------- QKV projections -> bf16 hi/lo operand layouts (reg-blocked) ----------------
// Qhi/Qlo/Khi/Klo: [B][N][C] bf16 ; Vb: [B][C][N] bf16
// grid: b * 8 o-groups * 32 voxel-blocks ; thread = 1 token, OG outputs x 3 mats
__global__ __launch_bounds__(256) void qkv_k(const float* __restrict__ f,
                      const float* __restrict__ wq, const float* __restrict__ bq,
                      const float* __restrict__ wk, const float* __restrict__ bk,
                      const float* __restrict__ wv, const float* __restrict__ bv,
                      unsigned short* __restrict__ Qhi, unsigned short* __restrict__ Qlo,
                      unsigned short* __restrict__ Khi, unsigned short* __restrict__ Klo,
                      unsigned short* __restrict__ Vb) {
    int blk = blockIdx.x;
    int vb  = blk & 31;
    int og  = (blk >> 5) & 7;       // uniform o-group
    int b   = blk >> 8;
    int n   = vb * 256 + threadIdx.x;
    bool valid = n < NSP;
    int nn  = valid ? n : 0;
    const float* fb = f + (size_t)b * COUT * NSP + nn;

    float aq[OG], ak[OG], av[OG];
    #pragma unroll
    for (int j = 0; j < OG; ++j) {
        int o = og * OG + j;
        aq[j] = bq[o]; ak[j] = bk[o]; av[j] = bv[o];
    }
    for (int c = 0; c < COUT; ++c) {
        float fc = fb[(size_t)c * NSP];
        #pragma unroll
        for (int j = 0; j < OG; ++j) {
            int o = og * OG + j;                         // uniform
            aq[j] += wq[o * COUT + c] * fc;
            ak[j] += wk[o * COUT + c] * fc;
            av[j] += wv[o * COUT + c] * fc;
        }
    }
    if (!valid) return;

    unsigned short qh[OG], ql[OG], kh[OG], kl[OG];
    #pragma unroll
    for (int j = 0; j < OG; ++j) {
        qh[j] = f2bf_rne(aq[j]); ql[j] = f2bf_rne(aq[j] - bf2f(qh[j]));
        kh[j] = f2bf_rne(ak[j]); kl[j] = f2bf_rne(ak[j] - bf2f(kh[j]));
    }
    size_t tq = ((size_t)(b * NSP + n)) * COUT + og * OG;
    *reinterpret_cast<uint4*>(Qhi + tq) = *reinterpret_cast<const uint4*>(qh);
    *reinterpret_cast<uint4*>(Qlo + tq) = *reinterpret_cast<const uint4*>(ql);
    *reinterpret_cast<uint4*>(Khi + tq) = *reinterpret_cast<const uint4*>(kh);
    *reinterpret_cast<uint4*>(Klo + tq) = *reinterpret_cast<const uint4*>(kl);
    #pragma unroll
    for (int j = 0; j < OG; ++j) {
        int o = og * OG + j;
        Vb[(size_t)(b * COUT + o) * NSP + n] = f2bf_rne(av[j]);
    }
}

// ---------------- flash attention pass 1: MFMA, split-K, online softmax ----------------
__global__ __launch_bounds__(128) void attn_pass1_mfma(
        const unsigned short* __restrict__ Qhi, const unsigned short* __restrict__ Qlo,
        const unsigned short* __restrict__ Khi, const unsigned short* __restrict__ Klo,
        const unsigned short* __restrict__ Vb,
        float* __restrict__ pm, float* __restrict__ pl, float* __restrict__ pacc) {
    int bid   = blockIdx.x;
    int split = bid % SPLITS;
    int qpair = (bid / SPLITS) % QPB;
    int b     = bid / (SPLITS * QPB);
    int wave  = threadIdx.x >> 6;
    int lane  = threadIdx.x & 63;
    int col   = lane & 31;
    int half  = lane >> 5;
    int q0    = (qpair * 2 + wave) * 32;
    int n0base = split * KPS;

    short8 qfh[4], qfl[4];
    {
        const unsigned short* qp  = Qhi + ((size_t)(b * NSP + q0 + col)) * COUT + half * 8;
        const unsigned short* qp2 = Qlo + ((size_t)(b * NSP + q0 + col)) * COUT + half * 8;
        #pragma unroll
        for (int c = 0; c < 4; ++c) {
            qfh[c] = ld_frag(qp  + c * 16);
            qfl[c] = ld_frag(qp2 + c * 16);
        }
    }

    f32x16 oacc0 = {};
    f32x16 oacc1 = {};
    float m = -3e38f, lsum = 0.f;

    for (int t = 0; t < NKT; ++t) {
        int n0 = n0base + t * 32;
        const unsigned short* kp  = Khi + ((size_t)(b * NSP + n0 + col)) * COUT + half * 8;
        const unsigned short* kp2 = Klo + ((size_t)(b * NSP + n0 + col)) * COUT + half * 8;
        f32x16 s = {};
        #pragma unroll
        for (int c = 0; c < 4; ++c) {
            short8 kfh = ld_frag(kp  + c * 16);
            short8 kfl = ld_frag(kp2 + c * 16);
            s = __builtin_amdgcn_mfma_f32_32x32x16_bf16(kfh, qfh[c], s, 0, 0, 0);
            s = __builtin_amdgcn_mfma_f32_32x32x16_bf16(kfh, qfl[c], s, 0, 0, 0);
            s = __builtin_amdgcn_mfma_f32_32x32x16_bf16(kfl, qfh[c], s, 0, 0, 0);
        }
        float tmax = s[0];
        #pragma unroll
        for (int r = 1; r < 16; ++r) tmax = fmaxf(tmax, s[r]);
        tmax = fmaxf(tmax, __shfl_xor(tmax, 32, 64));
        if (__any(tmax > m)) {
            float newm  = fmaxf(m, tmax);
            float scale = __expf(m - newm);
            lsum *= scale;
            #pragma unroll
            for (int r = 0; r < 16; ++r) { oacc0[r] *= scale; oacc1[r] *= scale; }
            m = newm;
        }
        float p[16]; float ls = 0.f;
        #pragma unroll
        for (int r = 0; r < 16; ++r) { p[r] = __expf(s[r] - m); ls += p[r]; }
        lsum += ls;
        unsigned W[8], X[8];
        #pragma unroll
        for (int j = 0; j < 8; ++j)
            asm("v_cvt_pk_bf16_f32 %0, %1, %2" : "=v"(W[j]) : "v"(p[2 * j]), "v"(p[2 * j + 1]));
        #pragma unroll
        for (int j = 0; j < 8; ++j) X[j] = (unsigned)__shfl_xor((int)W[j], 32, 64);
        uint4 u0, u1;
        if (half == 0) { u0 = make_uint4(W[0], W[1], X[0], X[1]); u1 = make_uint4(W[4], W[5], X[4], X[5]); }
        else           { u0 = make_uint4(X[2], X[3], W[2], W[3]); u1 = make_uint4(X[6], X[7], W[6], W[7]); }
        short8 pf0 = __builtin_bit_cast(short8, u0);
        short8 pf1 = __builtin_bit_cast(short8, u1);
        const unsigned short* vp = Vb + ((size_t)(b * COUT + col)) * NSP + n0 + half * 8;
        short8 v00 = ld_frag(vp);
        short8 v01 = ld_frag(vp + 16);
        short8 v10 = ld_frag(vp + (size_t)32 * NSP);
        short8 v11 = ld_frag(vp + (size_t)32 * NSP + 16);
        oacc0 = __builtin_amdgcn_mfma_f32_32x32x16_bf16(v00, pf0, oacc0, 0, 0, 0);
        oacc0 = __builtin_amdgcn_mfma_f32_32x32x16_bf16(v01, pf1, oacc0, 0, 0, 0);
        oacc1 = __builtin_amdgcn_mfma_f32_32x32x16_bf16(v10, pf0, oacc1, 0, 0, 0);
        oacc1 = __builtin_amdgcn_mfma_f32_32x32x16_bf16(v11, pf1, oacc1, 0, 0, 0);
    }

    float lfull = lsum + __shfl_xor(lsum, 32, 64);
    size_t base = (size_t)b * SPLITS + split;
    if (lane < 32) {
        pm[base * NSP + q0 + col] = m;
        pl[base * NSP + q0 + col] = lfull;
    }
    float* pa = pacc + base * (size_t)(COUT * NSP) + q0 + col;
    #pragma unroll
    for (int r = 0; r < 16; ++r) {
        int crow = (r & 3) + 8 * (r >> 2) + 4 * half;
        pa[(size_t)crow * NSP]        = oacc0[r];
        pa[(size_t)(crow + 32) * NSP] = oacc1[r];
    }
}

// ---------------- combine split-K partials ----------------
__global__ void attn_combine_k(const float* __restrict__ pm, const float* __restrict__ pl,
                               const float* __restrict__ pacc, float* __restrict__ out) {
    int idx = blockIdx.x * blockDim.x + threadIdx.x;   // over B*COUT*NSP
    if (idx >= BB * COUT * NSP) return;
    int n = idx % NSP;
    int c = (idx / NSP) % COUT;
    int b = idx / (NSP * COUT);
    float M = -1e30f;
    #pragma unroll
    for (int j = 0; j < SPLITS; ++j)
        M = fmaxf(M, pm[((size_t)b * SPLITS + j) * NSP + n]);
    float L = 0.f, O = 0.f;
    #pragma unroll
    for (int j = 0; j < SPLITS; ++j) {
        size_t base = (size_t)b * SPLITS + j;
        float wgt = __expf(pm[base * NSP + n] - M);
        L += pl[base * NSP + n] * wgt;
        O += pacc[(base * COUT + c) * NSP + n] * wgt;
    }
    out[idx] = O / L;
}

// ---------------- launch ----------------
extern "C" void kernel_launch(void* const* d_in, const int* in_sizes, int n_in,
                              void* d_out, int out_size, void* d_ws, size_t ws_size,
                              hipStream_t stream) {
    const float* x      = (const float*)d_in[0];
    const float* conv_w = (const float*)d_in[1];
    const float* conv_b = (const float*)d_in[2];
    const float* gamma  = (const float*)d_in[3];
    const float* beta   = (const float*)d_in[4];
    const float* wq     = (const float*)d_in[5];
    const float* bq     = (const float*)d_in[6];
    const float* wk     = (const float*)d_in[7];
    const float* bk     = (const float*)d_in[8];
    const float* wv     = (const float*)d_in[9];
    const float* bv     = (const float*)d_in[10];
    float* out = (float*)d_out;

    const int ELEMS = BB * COUT * NSP;      // 1,024,000
    char* w8 = (char*)d_ws;
    float* y     = (float*)w8;                          // 4,096,000 B
    float* stats = (float*)(w8 + 4096000);              // 1,024 B
    unsigned short* Qhi = (unsigned short*)(w8 + 4097024);
    unsigned short* Qlo = Qhi + (size_t)ELEMS;          // each 2,048,000 B
    unsigned short* Khi = Qlo + (size_t)ELEMS;
    unsigned short* Klo = Khi + (size_t)ELEMS;
    unsigned short* Vb  = Klo + (size_t)ELEMS;
    float* pm   = (float*)(Vb + (size_t)ELEMS);
    float* pl   = pm + (size_t)BB * SPLITS * NSP;       // 80,000 each
    float* pacc = pl + (size_t)BB * SPLITS * NSP;       // 20,480,000 B
    float* xpad = pacc + (size_t)BB * SPLITS * COUT * NSP;  // 2,725,888 B

    int blocks = (ELEMS + 255) / 256;       // 4000

    pad_k<<<(BB * CIN * PSP + 255) / 256, 256, 0, stream>>>(x, xpad);
    conv3d_k<<<BB * 8 * 32, 256, 0, stream>>>(xpad, conv_w, conv_b, y);
    instnorm_stats_k<<<BB * COUT, 256, 0, stream>>>(y, stats);
    norm_lrelu_k<<<blocks, 256, 0, stream>>>(y, stats, gamma, beta);
    qkv_k<<<BB * 8 * 32, 256, 0, stream>>>(y, wq, bq, wk, bk, wv, bv,
                                           Qhi, Qlo, Khi, Klo, Vb);
    attn_pass1_mfma<<<BB * QPB * SPLITS, 128, 0, stream>>>(Qhi, Qlo, Khi, Klo, Vb,
                                                           pm, pl, pacc);
    attn_combine_k<<<blocks, 256, 0, stream>>>(pm, pl, pacc, out);
}